// Round 2
// baseline (5790.452 us; speedup 1.0000x reference)
//
#include <hip/hip_runtime.h>
#include <stdint.h>

typedef unsigned int u32;
typedef unsigned long long u64;

#define CB 8
#define CT 512
#define CDIM 512
#define CR 2048
#define CH 8
#define CHD 64
#define CFFMAX 1368        // upper bound for workspace sizing only; real FF from in_sizes
#define CM 4096            // B*T
#define SCAN_WGS 64

// ======================= |w| sums (for ternary thresholds) =======================
__global__ __launch_bounds__(256) void k_abssum(const float* __restrict__ w, long n,
                                                double* __restrict__ sums, int idx){
  double s = 0.0;
  long stride = (long)gridDim.x * blockDim.x;
  for (long i = (long)blockIdx.x*blockDim.x + threadIdx.x; i < n; i += stride)
    s += (double)fabsf(w[i]);
  #pragma unroll
  for (int d = 32; d; d >>= 1) s += __shfl_down(s, d);
  __shared__ double ps[4];
  int lane = threadIdx.x & 63, wv = threadIdx.x >> 6;
  if (lane == 0) ps[wv] = s;
  __syncthreads();
  if (threadIdx.x == 0) atomicAdd(&sums[idx], ps[0]+ps[1]+ps[2]+ps[3]);
}

// ======================= ternary decode to f32 {-1,0,1} =======================
__global__ __launch_bounds__(256) void k_decode(const float* __restrict__ w, float* __restrict__ q,
                                                long n, const double* __restrict__ sums, int idx, double invN){
  double thr = 0.7 * (sums[idx] * invN);
  long stride = (long)gridDim.x * blockDim.x;
  for (long i = (long)blockIdx.x*blockDim.x + threadIdx.x; i < n; i += stride){
    float v = w[i];
    q[i] = (fabs((double)v) > thr) ? (v > 0.0f ? 1.0f : -1.0f) : 0.0f;
  }
}

// decode + transpose: w[rows][cols] -> qT[cols][rows]   (used for Wi)
__global__ __launch_bounds__(256) void k_decodeT(const float* __restrict__ w, float* __restrict__ qT,
                                                 long rows, long cols, const double* __restrict__ sums,
                                                 int idx, double invN){
  double thr = 0.7 * (sums[idx] * invN);
  long n = rows * cols;
  long stride = (long)gridDim.x * blockDim.x;
  for (long i = (long)blockIdx.x*blockDim.x + threadIdx.x; i < n; i += stride){
    long r = i / cols, d = i - r*cols;
    float v = w[i];
    float o = (fabs((double)v) > thr) ? (v > 0.0f ? 1.0f : -1.0f) : 0.0f;
    qT[d*rows + r] = o;
  }
}

// ======================= xp = x @ ternary(Wi)^T + bi   (float64 exact) =======================
// output layout xp[t][r][b]  (f64)
__global__ __launch_bounds__(256) void k_xp(const float* __restrict__ x, const float* __restrict__ wiqT,
                                            const float* __restrict__ bi, double* __restrict__ xp){
  int t = blockIdx.y;
  int r = blockIdx.x*256 + threadIdx.x;
  __shared__ double xs[CB][CDIM];          // 32 KB
  for (int i = threadIdx.x; i < CB*CDIM; i += 256){
    int b = i >> 9, d = i & 511;
    xs[b][d] = (double)x[((size_t)b*CT + t)*CDIM + d];
  }
  __syncthreads();
  double acc[CB];
  #pragma unroll
  for (int b = 0; b < CB; ++b) acc[b] = 0.0;
  for (int d = 0; d < CDIM; ++d){
    double wd = (double)wiqT[(size_t)d*CR + r];
    #pragma unroll
    for (int b = 0; b < CB; ++b) acc[b] = fma(wd, xs[b][d], acc[b]);
  }
  double bd = (double)bi[r];
  double* o = xp + ((size_t)t*CR + r)*CB;
  #pragma unroll
  for (int b = 0; b < CB; ++b) o[b] = acc[b] + bd;
}

// ======================= LIF reservoir scan (persistent, custom grid barrier) =======================
__global__ __launch_bounds__(256) void k_scan(const float* __restrict__ Wr,
                                              const double* __restrict__ xp,
                                              const float* __restrict__ beta,
                                              const float* __restrict__ sfi,
                                              const float* __restrict__ sfd,
                                              const double* __restrict__ sums,
                                              u32* __restrict__ acts,
                                              int* cnt, int* gen){
  __shared__ u64 masks[32][32][2];   // [word][row][pos/neg]  16 KB
  __shared__ u64 spkS[CB][32];       // [batch][word]          2 KB
  __shared__ unsigned char sbyte[CB][32];
  int tid = threadIdx.x;
  int g = blockIdx.x;
  int rbase = g * 32;
  double thr = 0.7 * (sums[1] * (1.0/((double)CR*(double)CR)));
  for (int wid = tid; wid < 1024; wid += 256){
    int row = wid >> 5, w = wid & 31;
    const float* wr = Wr + ((size_t)(rbase+row))*CR + w*64;
    u64 pos = 0, neg = 0;
    for (int jj = 0; jj < 64; jj += 4){
      float4 v4 = *reinterpret_cast<const float4*>(wr + jj);
      float vv[4] = {v4.x, v4.y, v4.z, v4.w};
      #pragma unroll
      for (int c = 0; c < 4; ++c){
        if (fabs((double)vv[c]) > thr){
          if (vv[c] > 0.0f) pos |= (1ull << (jj + c));
          else              neg |= (1ull << (jj + c));
        }
      }
    }
    masks[w][row][0] = pos;
    masks[w][row][1] = neg;
  }
  int row = tid >> 3, k = tid & 7;
  int r = rbase + row;
  double mem = 0.0, ath = 0.0;
  double bt = (double)beta[r], dc = (double)sfd[r], ic = (double)sfi[r];
  const double* xpr = xp + (size_t)r*CB + k;
  __syncthreads();
  double xv = xpr[0];
  for (int t = 0; t < CT; ++t){
    {
      int b2 = tid >> 5, w2 = tid & 31;
      u64 s = 0;
      if (t){
        const u32* p = acts + ((size_t)b2*CT + (t-1))*64 + 2*w2;
        s = ((u64)p[1] << 32) | (u64)p[0];
      }
      spkS[b2][w2] = s;
    }
    __syncthreads();
    double xv_next = (t+1 < CT) ? xpr[(size_t)(t+1)*CR*CB] : 0.0;
    int pa[8] = {0,0,0,0,0,0,0,0};
    int na[8] = {0,0,0,0,0,0,0,0};
    #pragma unroll
    for (int j = 0; j < 4; ++j){
      int w = k + 8*j;
      u64 pos = masks[w][row][0], neg = masks[w][row][1];
      #pragma unroll
      for (int b = 0; b < CB; ++b){
        u64 s = spkS[b][w];
        pa[b] += __popcll(s & pos);
        na[b] += __popcll(s & neg);
      }
    }
    int rec[8];
    #pragma unroll
    for (int b = 0; b < CB; ++b) rec[b] = pa[b] - na[b];
    #pragma unroll
    for (int b = 0; b < CB; ++b) rec[b] += __shfl_xor(rec[b], 1);
    #pragma unroll
    for (int b = 0; b < CB; ++b) rec[b] += __shfl_xor(rec[b], 2);
    #pragma unroll
    for (int b = 0; b < CB; ++b) rec[b] += __shfl_xor(rec[b], 4);
    double cur = xv + (double)rec[k];
    mem = bt*mem + cur;
    bool sp = (mem - (1.0 + ath)) > 0.0;
    mem = sp ? 0.0 : mem;
    ath = dc*ath + (sp ? ic : 0.0);
    sbyte[k][row] = sp ? 1 : 0;
    xv = xv_next;
    __syncthreads();
    if (tid < CB){
      const u32* sb = reinterpret_cast<const u32*>(&sbyte[tid][0]);
      u32 word = 0;
      #pragma unroll
      for (int i = 0; i < 8; ++i){
        u32 wv = sb[i];
        word |= ((wv & 1u) | ((wv >> 7) & 2u) | ((wv >> 14) & 4u) | ((wv >> 21) & 8u)) << (4*i);
      }
      acts[((size_t)tid*CT + t)*64 + g] = word;
    }
    __syncthreads();
    if (tid == 0){
      int old = __hip_atomic_fetch_add(cnt, 1, __ATOMIC_ACQ_REL, __HIP_MEMORY_SCOPE_AGENT);
      if (old == (t+1)*SCAN_WGS - 1){
        __hip_atomic_store(gen, t+1, __ATOMIC_RELEASE, __HIP_MEMORY_SCOPE_AGENT);
      } else {
        while (__hip_atomic_load(gen, __ATOMIC_ACQUIRE, __HIP_MEMORY_SCOPE_AGENT) < t+1) { }
      }
    }
    __syncthreads();
  }
}

// ======================= hn = rmsnorm(acts) * rn_w  (spikes are 0/1) =======================
__global__ __launch_bounds__(256) void k_hn(const u32* __restrict__ acts, const float* __restrict__ rn_w,
                                            float* __restrict__ hn){
  int rowbt = blockIdx.x;
  int b = rowbt >> 9, t = rowbt & 511;
  __shared__ u32 wlds[64];
  __shared__ int pc[64];
  __shared__ float sS;
  int tid = threadIdx.x;
  const u32* src = acts + ((size_t)b*CT + t)*64;
  if (tid < 64){ u32 w = src[tid]; wlds[tid] = w; pc[tid] = __popc(w); }
  __syncthreads();
  if (tid == 0){
    int c = 0;
    for (int i = 0; i < 64; ++i) c += pc[i];
    sS = 1.0f / sqrtf((float)c * (1.0f/(float)CR) + 1e-6f);
  }
  __syncthreads();
  float s = sS;
  #pragma unroll
  for (int i = 0; i < 8; ++i){
    int r = tid + 256*i;
    u32 w = wlds[r >> 5];
    float v = ((w >> (r & 31)) & 1u) ? s * rn_w[r] : 0.0f;
    hn[(size_t)rowbt*CR + r] = v;
  }
}

// ======================= generic f32 tiled GEMM =======================
// EPI: 0 none, 1 +bias->gelu, 2 +bias, 3 silu, 4 +res
struct GemmP {
  const float* A; long lda, Ab, Ah;
  const float* B; long ldb, Bb, Bh;
  float* C;       long ldc, Cb, Ch;
  const float* bias;
  const float* res; long ldr, Rb, Rh;
  float scale;
  int M, N, K, HH;
};

template<int EPI, bool BT>
__global__ __launch_bounds__(256) void k_gemm(GemmP p){
  int bz = blockIdx.z;
  int bb = bz / p.HH, hh = bz - bb*p.HH;
  const float* A = p.A + (size_t)bb*p.Ab + (size_t)hh*p.Ah;
  const float* B = p.B + (size_t)bb*p.Bb + (size_t)hh*p.Bh;
  float* C = p.C + (size_t)bb*p.Cb + (size_t)hh*p.Ch;
  const float* R = p.res ? (p.res + (size_t)bb*p.Rb + (size_t)hh*p.Rh) : (const float*)0;
  int m0 = blockIdx.y*64, n0 = blockIdx.x*64;
  __shared__ float As[32][68];
  __shared__ float Bs[32][68];
  int tid = threadIdx.x;
  int tx = tid & 15, ty = tid >> 4;
  float acc[4][4] = {{0,0,0,0},{0,0,0,0},{0,0,0,0},{0,0,0,0}};
  for (int k0 = 0; k0 < p.K; k0 += 32){
    #pragma unroll
    for (int l = 0; l < 8; ++l){
      int lin = tid + 256*l;
      int mm = lin >> 5, kk = lin & 31;
      int gm = m0 + mm, gk = k0 + kk;
      float v = 0.0f;
      if (gm < p.M && gk < p.K) v = A[(size_t)gm*p.lda + gk];
      As[kk][mm] = v;
    }
    #pragma unroll
    for (int l = 0; l < 8; ++l){
      int lin = tid + 256*l;
      float v = 0.0f;
      if (BT){
        int nn = lin >> 5, kk = lin & 31;
        int gn = n0 + nn, gk = k0 + kk;
        if (gn < p.N && gk < p.K) v = B[(size_t)gn*p.ldb + gk];
        Bs[kk][nn] = v;
      } else {
        int kk = lin >> 6, nn = lin & 63;
        int gk = k0 + kk, gn = n0 + nn;
        if (gk < p.K && gn < p.N) v = B[(size_t)gk*p.ldb + gn];
        Bs[kk][nn] = v;
      }
    }
    __syncthreads();
    #pragma unroll
    for (int kk = 0; kk < 32; ++kk){
      float a[4], bv[4];
      #pragma unroll
      for (int i = 0; i < 4; ++i) a[i] = As[kk][ty*4 + i];
      #pragma unroll
      for (int j = 0; j < 4; ++j) bv[j] = Bs[kk][tx*4 + j];
      #pragma unroll
      for (int i = 0; i < 4; ++i)
        #pragma unroll
        for (int j = 0; j < 4; ++j)
          acc[i][j] = fmaf(a[i], bv[j], acc[i][j]);
    }
    __syncthreads();
  }
  #pragma unroll
  for (int i = 0; i < 4; ++i){
    int gm = m0 + ty*4 + i;
    if (gm >= p.M) continue;
    #pragma unroll
    for (int j = 0; j < 4; ++j){
      int gn = n0 + tx*4 + j;
      if (gn >= p.N) continue;
      float v = acc[i][j] * p.scale;
      if (EPI == 1){ v += p.bias[gn]; v = 0.5f*v*(1.0f + erff(v*0.7071067811865475f)); }
      else if (EPI == 2){ v += p.bias[gn]; }
      else if (EPI == 3){ v = v / (1.0f + expf(-v)); }
      else if (EPI == 4){ v += R[(size_t)gm*p.ldr + gn]; }
      C[(size_t)gm*p.ldc + gn] = v;
    }
  }
}

template<int EPI, bool BT>
static void run_gemm(const GemmP& p, hipStream_t s, int nbat){
  dim3 grid((p.N + 63)/64, (p.M + 63)/64, nbat), blk(256);
  k_gemm<EPI, BT><<<grid, blk, 0, s>>>(p);
}

// ======================= row softmax (512 cols), in place =======================
__global__ __launch_bounds__(256) void k_softmax(float* __restrict__ sc, long rows){
  long gw = ((long)blockIdx.x*blockDim.x + threadIdx.x) >> 6;
  int lane = threadIdx.x & 63;
  if (gw >= rows) return;
  float* row = sc + gw*512;
  float4 v1 = *reinterpret_cast<const float4*>(row + lane*8);
  float4 v2 = *reinterpret_cast<const float4*>(row + lane*8 + 4);
  float v[8] = {v1.x, v1.y, v1.z, v1.w, v2.x, v2.y, v2.z, v2.w};
  float mx = v[0];
  #pragma unroll
  for (int e = 1; e < 8; ++e) mx = fmaxf(mx, v[e]);
  #pragma unroll
  for (int d = 32; d; d >>= 1) mx = fmaxf(mx, __shfl_xor(mx, d));
  float sum = 0.0f;
  #pragma unroll
  for (int e = 0; e < 8; ++e){ v[e] = expf(v[e] - mx); sum += v[e]; }
  #pragma unroll
  for (int d = 32; d; d >>= 1) sum += __shfl_xor(sum, d);
  float inv = 1.0f / sum;
  float4 o1 = make_float4(v[0]*inv, v[1]*inv, v[2]*inv, v[3]*inv);
  float4 o2 = make_float4(v[4]*inv, v[5]*inv, v[6]*inv, v[7]*inv);
  *reinterpret_cast<float4*>(row + lane*8) = o1;
  *reinterpret_cast<float4*>(row + lane*8 + 4) = o2;
}

// ======================= rmsnorm rows of 512 =======================
__global__ __launch_bounds__(256) void k_rmsnorm(const float* __restrict__ x, const float* __restrict__ w,
                                                 float* __restrict__ o, long rows){
  long gw = ((long)blockIdx.x*blockDim.x + threadIdx.x) >> 6;
  int lane = threadIdx.x & 63;
  if (gw >= rows) return;
  const float* xr = x + gw*512;
  float v[8]; float ss = 0.0f;
  #pragma unroll
  for (int e = 0; e < 8; ++e){ v[e] = xr[lane*8 + e]; ss = fmaf(v[e], v[e], ss); }
  #pragma unroll
  for (int d = 32; d; d >>= 1) ss += __shfl_xor(ss, d);
  float r = 1.0f / sqrtf(ss*(1.0f/512.0f) + 1e-6f);
  float* orow = o + gw*512;
  #pragma unroll
  for (int e = 0; e < 8; ++e) orow[lane*8 + e] = v[e]*r*w[lane*8 + e];
}

// ======================= elementwise g *= u =======================
__global__ __launch_bounds__(256) void k_mul(float* __restrict__ g, const float* __restrict__ u, long n){
  long stride = (long)gridDim.x * blockDim.x;
  for (long i = (long)blockIdx.x*blockDim.x + threadIdx.x; i < n; i += stride) g[i] *= u[i];
}

// ======================= host =======================
extern "C" void kernel_launch(void* const* d_in, const int* in_sizes, int n_in,
                              void* d_out, int out_size, void* d_ws, size_t ws_size,
                              hipStream_t stream){
  (void)n_in; (void)out_size;
  const float* x    = (const float*)d_in[0];
  const float* Wi   = (const float*)d_in[1];
  const float* bi   = (const float*)d_in[2];
  const float* Wr   = (const float*)d_in[3];
  const float* rn_w = (const float*)d_in[4];
  const float* W1   = (const float*)d_in[5];
  const float* b1   = (const float*)d_in[6];
  const float* W2   = (const float*)d_in[7];
  const float* b2   = (const float*)d_in[8];
  const float* anw  = (const float*)d_in[9];
  const float* Wqkv = (const float*)d_in[10];
  const float* Wo   = (const float*)d_in[11];
  const float* fnw  = (const float*)d_in[12];
  const float* Wf1  = (const float*)d_in[13];
  const float* Wf2  = (const float*)d_in[14];
  const float* Wf3  = (const float*)d_in[15];
  const float* beta = (const float*)d_in[16];
  const float* sfi  = (const float*)d_in[17];
  const float* sfd  = (const float*)d_in[18];

  // FFH = int(DIM*2.66) = 1361 (NOT 1362 — the reference comment is wrong).
  // Derive from actual input size to be safe: Wf1 is [FF, DIM].
  const long FF = (long)in_sizes[13] / CDIM;

  char* ws = (char*)d_ws;
  size_t cur = 0;
  auto alloc = [&](size_t bytes){ size_t o = cur; cur += (bytes + 255) & ~(size_t)255; return o; };
  size_t oCTRL = alloc(4096);
  size_t oACTS = alloc((size_t)CB*CT*64*4);            // 1 MB  spike bits
  size_t oXP   = alloc((size_t)CT*CR*CB*8);            // 64 MB f64 xp; reused as scores f32[64][512][512]
  size_t oWIQT = alloc((size_t)CDIM*CR*4);
  size_t oW1Q  = alloc((size_t)1024*CR*4);
  size_t oW2Q  = alloc((size_t)512*1024*4);
  size_t oWQKV = alloc((size_t)1536*512*4);
  size_t oWOQ  = alloc((size_t)512*512*4);
  size_t oWF1Q = alloc((size_t)CFFMAX*512*4);
  size_t oWF2Q = alloc((size_t)512*CFFMAX*4);
  size_t oWF3Q = alloc((size_t)CFFMAX*512*4);
  size_t oHN   = alloc((size_t)CM*CR*4);               // hn; reused as g
  size_t oH    = alloc((size_t)CM*1024*4);
  size_t oY    = alloc((size_t)CM*512*4);
  size_t oXA   = alloc((size_t)CM*512*4);              // xa; reused as xf
  size_t oQKV  = alloc((size_t)CM*1536*4);             // qkv; reused as u
  size_t oO    = alloc((size_t)CM*512*4);
  size_t oXR   = alloc((size_t)CM*512*4);
  if (cur > ws_size) return;

  double* sums = (double*)(ws + oCTRL + 128);
  int* cnt = (int*)(ws + oCTRL);
  int* gen = (int*)(ws + oCTRL + 64);
  u32* uACTS = (u32*)(ws + oACTS);
  double* dXP = (double*)(ws + oXP);
  float* fSC  = (float*)(ws + oXP);
  float* fWIQT = (float*)(ws + oWIQT);
  float* fW1Q = (float*)(ws + oW1Q);
  float* fW2Q = (float*)(ws + oW2Q);
  float* fWQKV = (float*)(ws + oWQKV);
  float* fWOQ = (float*)(ws + oWOQ);
  float* fWF1Q = (float*)(ws + oWF1Q);
  float* fWF2Q = (float*)(ws + oWF2Q);
  float* fWF3Q = (float*)(ws + oWF3Q);
  float* fHN = (float*)(ws + oHN);
  float* fG  = (float*)(ws + oHN);
  float* fH  = (float*)(ws + oH);
  float* fY  = (float*)(ws + oY);
  float* fXA = (float*)(ws + oXA);
  float* fQKV = (float*)(ws + oQKV);
  float* fU  = (float*)(ws + oQKV);
  float* fO  = (float*)(ws + oO);
  float* fXR = (float*)(ws + oXR);
  float* out = (float*)d_out;

  dim3 b256(256);
  hipMemsetAsync(ws + oCTRL, 0, 4096, stream);

  k_abssum<<<512, b256, 0, stream>>>(Wi,  (long)CR*CDIM,  sums, 0);
  k_abssum<<<512, b256, 0, stream>>>(Wr,  (long)CR*CR,    sums, 1);
  k_abssum<<<512, b256, 0, stream>>>(W1,  (long)1024*CR,  sums, 2);
  k_abssum<<<512, b256, 0, stream>>>(W2,  (long)512*1024, sums, 3);
  k_abssum<<<512, b256, 0, stream>>>(Wqkv,(long)1536*512, sums, 4);
  k_abssum<<<512, b256, 0, stream>>>(Wo,  (long)512*512,  sums, 5);
  k_abssum<<<512, b256, 0, stream>>>(Wf1, FF*512,         sums, 6);
  k_abssum<<<512, b256, 0, stream>>>(Wf2, 512*FF,         sums, 7);
  k_abssum<<<512, b256, 0, stream>>>(Wf3, FF*512,         sums, 8);

  k_decodeT<<<1024, b256, 0, stream>>>(Wi, fWIQT, CR, CDIM, sums, 0, 1.0/((double)CR*CDIM));
  k_decode<<<1024, b256, 0, stream>>>(W1,  fW1Q, (long)1024*CR,  sums, 2, 1.0/((double)1024*CR));
  k_decode<<<1024, b256, 0, stream>>>(W2,  fW2Q, (long)512*1024, sums, 3, 1.0/((double)512*1024));
  k_decode<<<1024, b256, 0, stream>>>(Wqkv,fWQKV,(long)1536*512, sums, 4, 1.0/((double)1536*512));
  k_decode<<<1024, b256, 0, stream>>>(Wo,  fWOQ, (long)512*512,  sums, 5, 1.0/((double)512*512));
  k_decode<<<1024, b256, 0, stream>>>(Wf1, fWF1Q, FF*512,        sums, 6, 1.0/((double)FF*512));
  k_decode<<<1024, b256, 0, stream>>>(Wf2, fWF2Q, 512*FF,        sums, 7, 1.0/((double)FF*512));
  k_decode<<<1024, b256, 0, stream>>>(Wf3, fWF3Q, FF*512,        sums, 8, 1.0/((double)FF*512));

  k_xp<<<dim3(CR/256, CT), b256, 0, stream>>>(x, fWIQT, bi, dXP);
  k_scan<<<SCAN_WGS, b256, 0, stream>>>(Wr, dXP, beta, sfi, sfd, sums, uACTS, cnt, gen);
  k_hn<<<CM, b256, 0, stream>>>(uACTS, rn_w, fHN);

  // h = gelu(hn @ W1q^T + b1)
  { GemmP p{fHN, CR,0,0,  fW1Q, CR,0,0,  fH, 1024,0,0,  b1,  (const float*)0,0,0,0, 1.0f, CM,1024,CR,1};
    run_gemm<1,true>(p, stream, 1); }
  // y = h @ W2q^T + b2
  { GemmP p{fH, 1024,0,0, fW2Q, 1024,0,0, fY, 512,0,0,  b2,  (const float*)0,0,0,0, 1.0f, CM,512,1024,1};
    run_gemm<2,true>(p, stream, 1); }
  k_rmsnorm<<<CM/4, b256, 0, stream>>>(fY, anw, fXA, CM);
  // qkv = xa @ Wqkv^T
  { GemmP p{fXA, 512,0,0, fWQKV, 512,0,0, fQKV, 1536,0,0, (const float*)0, (const float*)0,0,0,0, 1.0f, CM,1536,512,1};
    run_gemm<0,true>(p, stream, 1); }
  // scores[b,h] = q @ k^T * 0.125
  { GemmP p{fQKV,       1536, 786432, 64,
            fQKV + 512, 1536, 786432, 64,
            fSC,        512,  2097152, 262144,
            (const float*)0, (const float*)0,0,0,0, 0.125f, 512,512,64,CH};
    run_gemm<0,true>(p, stream, CB*CH); }
  k_softmax<<<(long)CB*CH*512/4, b256, 0, stream>>>(fSC, (long)CB*CH*512);
  // o[b,h] = attn @ v
  { GemmP p{fSC,         512,  2097152, 262144,
            fQKV + 1024, 1536, 786432,  64,
            fO,          512,  262144,  64,
            (const float*)0, (const float*)0,0,0,0, 1.0f, 512,64,512,CH};
    run_gemm<0,false>(p, stream, CB*CH); }
  // x_res = y + o @ Wo^T
  { GemmP p{fO, 512,0,0, fWOQ, 512,0,0, fXR, 512,0,0, (const float*)0, fY, 512,0,0, 1.0f, CM,512,512,1};
    run_gemm<4,true>(p, stream, 1); }
  k_rmsnorm<<<CM/4, b256, 0, stream>>>(fXR, fnw, fXA, CM);
  // g = silu(xf @ Wf1^T)
  { GemmP p{fXA, 512,0,0, fWF1Q, 512,0,0, fG, FF,0,0, (const float*)0, (const float*)0,0,0,0, 1.0f, CM,(int)FF,512,1};
    run_gemm<3,true>(p, stream, 1); }
  // u = xf @ Wf3^T
  { GemmP p{fXA, 512,0,0, fWF3Q, 512,0,0, fU, FF,0,0, (const float*)0, (const float*)0,0,0,0, 1.0f, CM,(int)FF,512,1};
    run_gemm<0,true>(p, stream, 1); }
  k_mul<<<2048, b256, 0, stream>>>(fG, fU, (long)CM*FF);
  // out = x_res + (g*u) @ Wf2^T
  { GemmP p{fG, FF,0,0, fWF2Q, FF,0,0, out, 512,0,0, (const float*)0, fXR, 512,0,0, 1.0f, CM,512,(int)FF,1};
    run_gemm<4,true>(p, stream, 1); }
}